// Round 1
// baseline (227.549 us; speedup 1.0000x reference)
//
#include <hip/hip_runtime.h>

typedef __attribute__((ext_vector_type(8))) short short8;
typedef __attribute__((ext_vector_type(4))) float floatx4;

#define LDS_X  0       // 64 rows x 512 B (bf16, swizzled)
#define LDS_WT 32768   // 64 rows x 512 B (bf16, swizzled); reused for ea[64] after GEMM

__device__ __forceinline__ unsigned short f2bf(float f) {
    unsigned int u = __float_as_uint(f);
    u += 0x7FFFu + ((u >> 16) & 1u);   // round-to-nearest-even
    return (unsigned short)(u >> 16);
}
__device__ __forceinline__ float bf2f(unsigned short h) {
    return __uint_as_float(((unsigned int)h) << 16);
}

// W (256x256 f32, [k][n]) -> Wt bf16 [n][k] (coalesced both sides via LDS tile)
__global__ __launch_bounds__(256) void k_wt(const float* __restrict__ W,
                                            unsigned short* __restrict__ Wt) {
    __shared__ unsigned short tile[64][65];
    const int kt = blockIdx.x >> 2, nt = blockIdx.x & 3;
    const int t = threadIdx.x, c = t & 63, rb = t >> 6;
#pragma unroll
    for (int i = 0; i < 16; ++i) {
        int r = i * 4 + rb;
        tile[c][r] = f2bf(W[(kt * 64 + r) * 256 + nt * 64 + c]);
    }
    __syncthreads();
#pragma unroll
    for (int i = 0; i < 16; ++i) {
        int n = i * 4 + rb;
        Wt[(nt * 64 + n) * 256 + kt * 64 + c] = tile[n][c];
    }
}

// Per block: 64 rows of x, full K=256, full N=256.
// GEMM(bf16 MFMA) + tanh + dot(u) + exp -> ea ; fused numerator partial.
__global__ __launch_bounds__(256) void k_main(
        const float* __restrict__ x, const unsigned short* __restrict__ Wt,
        const float* __restrict__ bias, const float* __restrict__ u,
        float* __restrict__ ea_all, float* __restrict__ num) {
    __shared__ __align__(16) unsigned char lds[65536];
    const int tid = threadIdx.x;
    const int lane = tid & 63;
    const int wv = tid >> 6;           // wave 0..3, owns rows wv*16..+15
    const int m0 = blockIdx.x << 6;    // global row base (64 | 2048 -> no batch crossing)
    const int batch = m0 >> 11;

    // ---- stage x tile: fp32 -> bf16, XOR-swizzled rows of 512 B ----
    {
        const int rr = tid >> 5;           // 8 rows per pass
        const int kf = (tid & 31) << 3;    // 8 floats per thread, coalesced
#pragma unroll
        for (int p = 0; p < 8; ++p) {
            const int r = (p << 3) + rr;
            const float* src = x + (size_t)(m0 + r) * 256 + kf;
            const float4 v0 = *(const float4*)(src);
            const float4 v1 = *(const float4*)(src + 4);
            short8 pk;
            pk[0] = (short)f2bf(v0.x); pk[1] = (short)f2bf(v0.y);
            pk[2] = (short)f2bf(v0.z); pk[3] = (short)f2bf(v0.w);
            pk[4] = (short)f2bf(v1.x); pk[5] = (short)f2bf(v1.y);
            pk[6] = (short)f2bf(v1.z); pk[7] = (short)f2bf(v1.w);
            const int addr = (r << 9) + ((kf << 1) ^ ((r & 7) << 4));
            *(short8*)(lds + LDS_X + addr) = pk;
        }
    }
    __syncthreads();

    // ---- A fragments: this wave's 16 rows, all 8 K-steps (kept in regs) ----
    short8 afrag[8];
    {
        const int r = (wv << 4) + (lane & 15);
        const int swz = (r & 7) << 4;
#pragma unroll
        for (int ks = 0; ks < 8; ++ks) {
            const int cb = (ks << 6) + ((lane >> 4) << 4);
            afrag[ks] = *(const short8*)(lds + LDS_X + (r << 9) + (cb ^ swz));
        }
    }

    floatx4 acc[16];
#pragma unroll
    for (int i = 0; i < 16; ++i) acc[i] = floatx4{0.f, 0.f, 0.f, 0.f};

    // ---- K-complete GEMM over 4 n-chunks of 64 cols (Wt rows) ----
#pragma unroll
    for (int g = 0; g < 4; ++g) {
        __syncthreads();  // prior chunk's reads done before overwrite
#pragma unroll
        for (int i = 0; i < 8; ++i) {   // 32 KB linear global -> swizzled LDS
            const int d = (i << 12) + (tid << 4);
            const short8 v = *(const short8*)((const unsigned char*)Wt + (g << 15) + d);
            const int a = d ^ (((d >> 9) & 7) << 4);
            *(short8*)(lds + LDS_WT + a) = v;
        }
        __syncthreads();
#pragma unroll
        for (int nt = 0; nt < 4; ++nt) {
            const int row = (nt << 4) + (lane & 15);
            const int base = row << 9;
            const int swz = (row & 7) << 4;
#pragma unroll
            for (int ks = 0; ks < 8; ++ks) {
                const int cb = (ks << 6) + ((lane >> 4) << 4);
                const short8 bfrag = *(const short8*)(lds + LDS_WT + base + (cb ^ swz));
                acc[g * 4 + nt] = __builtin_amdgcn_mfma_f32_16x16x32_bf16(
                    afrag[ks], bfrag, acc[g * 4 + nt], 0, 0, 0);
            }
        }
    }
    __syncthreads();   // all waves done with wt_lds -> reuse region for ea

    // ---- tanh + dot(u): C/D layout col=lane&15, row=(lane>>4)*4+j (m89) ----
    float p4[4] = {0.f, 0.f, 0.f, 0.f};
#pragma unroll
    for (int n16 = 0; n16 < 16; ++n16) {
        const int col = (n16 << 4) + (lane & 15);
        const float uu = u[col];
        const float bb = bias[col];
#pragma unroll
        for (int j = 0; j < 4; ++j) {
            const float v = acc[n16][j] + bb;
            const float e = __expf(2.0f * v);                       // v_exp_f32
            const float th = 1.0f - 2.0f * __builtin_amdgcn_rcpf(e + 1.0f); // safe at inf
            p4[j] += th * uu;
        }
    }
    float* ea_lds = (float*)(lds + LDS_WT);
#pragma unroll
    for (int j = 0; j < 4; ++j) {
        float s = p4[j];
        s += __shfl_xor(s, 1);
        s += __shfl_xor(s, 2);
        s += __shfl_xor(s, 4);
        s += __shfl_xor(s, 8);          // sum over the 16 col-lanes
        const float ea = __expf(s);     // ref: exp with no max-subtract
        const int lrow = (wv << 4) + ((lane >> 4) << 2) + j;
        if ((lane & 15) == 0) {
            ea_lds[lrow] = ea;
            ea_all[m0 + lrow] = ea;
        }
    }
    __syncthreads();

    // ---- fused numerator partial: thread owns f = tid, x read back from LDS ----
    {
        float s0 = 0.f;
        const int fb = tid << 1;
#pragma unroll 8
        for (int r = 0; r < 64; ++r) {
            const float ea = ea_lds[r];   // broadcast
            const int a = (r << 9) + (fb ^ ((r & 7) << 4));
            s0 += bf2f(*(const unsigned short*)(lds + LDS_X + a)) * ea;
        }
        atomicAdd(&num[batch * 256 + tid], s0);
    }
}

// denom per batch + finalize
__global__ __launch_bounds__(256) void k_final(const float* __restrict__ ea_all,
                                               const float* __restrict__ num,
                                               float* __restrict__ out) {
    __shared__ float red[8];
    const int b = blockIdx.x, tid = threadIdx.x;
    float s = 0.f;
#pragma unroll
    for (int i = 0; i < 8; ++i) s += ea_all[(b << 11) + (i << 8) + tid];
    s += __shfl_xor(s, 1);  s += __shfl_xor(s, 2);  s += __shfl_xor(s, 4);
    s += __shfl_xor(s, 8);  s += __shfl_xor(s, 16); s += __shfl_xor(s, 32);
    if ((tid & 63) == 0) red[tid >> 6] = s;
    __syncthreads();
    if (tid == 0) red[4] = 1.0f / (red[0] + red[1] + red[2] + red[3] + 1e-7f);
    __syncthreads();
    out[(b << 8) + tid] = num[(b << 8) + tid] * red[4];
}

extern "C" void kernel_launch(void* const* d_in, const int* in_sizes, int n_in,
                              void* d_out, int out_size, void* d_ws, size_t ws_size,
                              hipStream_t stream) {
    const float* x    = (const float*)d_in[0];
    const float* W    = (const float*)d_in[1];
    const float* bias = (const float*)d_in[2];
    const float* u    = (const float*)d_in[3];
    float* out = (float*)d_out;
    unsigned char* ws = (unsigned char*)d_ws;
    unsigned short* Wt = (unsigned short*)(ws);            // 131072 B
    float* ea_all      = (float*)(ws + 131072);            // 524288 B
    float* num         = (float*)(ws + 131072 + 524288);   // 65536 B

    hipMemsetAsync(num, 0, 65536, stream);
    k_wt<<<16, 256, 0, stream>>>(W, Wt);
    k_main<<<2048, 256, 0, stream>>>(x, Wt, bias, u, ea_all, num);
    k_final<<<64, 256, 0, stream>>>(ea_all, num, out);
}